// Round 9
// baseline (197.300 us; speedup 1.0000x reference)
//
#include <hip/hip_runtime.h>

#define B 8
#define P 2048
#define C 1024
#define NCHUNK 32
#define FEAT4 (B*P*C/4)   // 4194304 float4s of features
#define CEN4  (B*P*3/4)   // 12288 float4s of centers (and of cls_preds)

typedef unsigned long long u64;
typedef unsigned int u32;
typedef float f4 __attribute__((ext_vector_type(4)));   // NT-builtin-legal 16B vector

// ---------------------------------------------------------------------------
// K1: full-GPU rank sort (R7, unchanged). Keys unique => rank is a bijection.
// ---------------------------------------------------------------------------
__global__ __launch_bounds__(512) void rank_kernel(
    const float* __restrict__ centers,
    const float* __restrict__ cls_preds,
    float4* __restrict__ scent,
    int* __restrict__ sidx)
{
    __shared__ u64 s_keys[P];       // 16 KB
    __shared__ u32 s_cnt[64][9];    // padded reduce buffer
    const int b = blockIdx.x >> 5, gi = blockIdx.x & 31;
    const int tid = threadIdx.x, wv = tid >> 6, lane = tid & 63;
    const float* clsb = cls_preds + (size_t)b * P * 3;
    const float* cenb = centers + (size_t)b * P * 3;

    for (int e = tid; e < P; e += 512) {
        float s0 = clsb[e*3], s1 = clsb[e*3+1], s2 = clsb[e*3+2];
        float sc = s0; int lb = 0;
        if (s1 > sc) { sc = s1; lb = 1; }
        if (s2 > sc) { sc = s2; lb = 2; }
        u32 ub = __float_as_uint(sc);
        u32 ord = (ub & 0x80000000u) ? ~ub : (ub | 0x80000000u);
        s_keys[e] = ((u64)(~ord) << 32) | (u32)((e << 2) | lb);
    }
    __syncthreads();

    const u64 myk = s_keys[(gi << 6) + lane];
    u32 c = 0;
    const int sbase = wv << 8;
    #pragma unroll 8
    for (int u = 0; u < 256; ++u)            // wave-uniform -> broadcast, free
        c += (s_keys[sbase + u] < myk) ? 1u : 0u;
    s_cnt[lane][wv] = c;
    __syncthreads();

    if (wv == 0) {
        u32 rank = 0;
        #pragma unroll
        for (int s = 0; s < 8; ++s) rank += s_cnt[lane][s];
        u32 lo = (u32)myk;
        int orig = (int)(lo >> 2);
        float4 cc;
        cc.x = cenb[orig*3]; cc.y = cenb[orig*3+1]; cc.z = cenb[orig*3+2];
        cc.w = __int_as_float((int)(lo & 3));
        scent[(size_t)b * P + rank] = cc;
        sidx[(size_t)b * P + rank] = (int)lo;
    }
}

// ---------------------------------------------------------------------------
// K2: suppression rows, TRIANGLE-TRIMMED: scan only reads matT[w][i] for
// w >= 2*(i/64) (own-chunk resolve words + future update words), so words
// below the chunk-diagonal are never computed or stored -> half the work.
// ---------------------------------------------------------------------------
__global__ __launch_bounds__(512) void matrix_kernel(
    const float4* __restrict__ scent,
    const float* __restrict__ class_radius,
    u32* __restrict__ matT)
{
    __shared__ float4 s_cent[P];   // 32 KB
    const int b = blockIdx.x >> 5, gi = blockIdx.x & 31;
    const int tid = threadIdx.x, wv = tid >> 6, lane = tid & 63;

    const float4 cj = scent[(size_t)b * P + (gi << 6) + lane];  // coalesced
    const int labj = __float_as_int(cj.w);
    const float r = class_radius[labj];
    const float r2 = r * r;
    const int wmin = gi << 1;

    for (int i = tid; i < P; i += 512) s_cent[i] = scent[(size_t)b * P + i];
    __syncthreads();

    for (int w = wv; w < 64; w += 8) {
        if (w < wmin) continue;                       // dead sub-diagonal
        u32 acc = 0;
        #pragma unroll
        for (int u = 0; u < 32; ++u) {
            float4 ci = s_cent[(w << 5) + u];         // uniform -> broadcast
            float dx = cj.x - ci.x, dy = cj.y - ci.y, dz = cj.z - ci.z;
            bool sup = (__float_as_int(ci.w) == labj)
                       && (dx*dx + dy*dy + dz*dz < r2);
            acc |= ((u32)sup) << u;
        }
        matT[((size_t)b * 64 + w) * P + (gi << 6) + lane] = acc;  // coalesced
    }
}

// ---------------------------------------------------------------------------
// K3: greedy resolution, one block (9 waves) per scene, one barrier/chunk.
// Waves 1..8: double-buffered prefetch of next chunk's padded tile, words
// w >= 2*(g+1) only (triangle trim; stale lower words OR garbage only into
// removed-words indexing already-processed chunks -- never read again).
// Wave 0: removed bitmap in REGISTERS (word `lane` in a VGPR, rem via 2
// shfls), parallel-peeling resolve (== sequential greedy), keep scatter,
// incremental removed-update from the kept rows.
// ---------------------------------------------------------------------------
__global__ __launch_bounds__(576) void scan_kernel(
    const u32* __restrict__ matT,
    const int* __restrict__ sidx,
    float* __restrict__ out_keep)
{
    __shared__ u32 s_tile[2][64][65];   // [buf][q][w]; row reads 2-way (free),
                                        // update reads bank (q+lane)&31: clean
    __shared__ int s_sidx[P];
    const int b = blockIdx.x;
    const int tid = threadIdx.x, wv = tid >> 6, lane = tid & 63;
    const u32* mb = matT + (size_t)b * 64 * P;

    for (int i = tid; i < P; i += 576) s_sidx[i] = sidx[(size_t)b * P + i];
    if (wv >= 1) {                       // stage chunk 0 (all 64 words)
        #pragma unroll
        for (int rr = 0; rr < 8; ++rr) {
            int w = (wv - 1) + (rr << 3);
            s_tile[0][lane][w] = mb[(size_t)w * P + lane];
        }
    }
    __syncthreads();

    u32 rw = 0;                          // wave0: removed word `lane`

    for (int g = 0; g < NCHUNK; ++g) {
        const int buf = g & 1;
        if (wv >= 1 && g + 1 < NCHUNK) { // prefetch chunk g+1, w >= 2(g+1)
            const int nb = (g + 1) << 6, wmin = (g + 1) << 1;
            #pragma unroll
            for (int rr = 0; rr < 8; ++rr) {
                int w = (wv - 1) + (rr << 3);
                if (w >= wmin)
                    s_tile[buf ^ 1][lane][w] = mb[(size_t)w * P + nb + lane];
            }
        }
        if (wv == 0) {
            const int base = g << 6;
            u64 row = (u64)s_tile[buf][lane][2*g]
                    | ((u64)s_tile[buf][lane][2*g + 1] << 32);
            u32 r0 = (u32)__shfl((int)rw, 2*g, 64);
            u32 r1 = (u32)__shfl((int)rw, 2*g + 1, 64);
            u64 alive = ~((u64)r0 | ((u64)r1 << 32));
            const u64 below = (1ull << lane) - 1ull;
            u64 keepm = 0;
            while (alive) {              // peeling: rounds = chain depth
                bool ok = ((alive >> lane) & 1ull) && ((row & alive & below) == 0ull);
                u64 newk = __ballot(ok);
                keepm |= newk;
                bool dead = (row & newk) != 0ull;
                u64 deadm = __ballot(dead);
                alive &= ~(newk | deadm);
            }
            int orig = s_sidx[base + lane] >> 2;
            out_keep[(size_t)b * P + orig] = ((keepm >> lane) & 1ull) ? 1.0f : 0.0f;
            // incremental removed update: lane == word index; garbage in
            // words < 2g harmless (those chunks already resolved)
            u32 acc = 0;
            u64 m = keepm;
            while (m) {
                int q = (int)__ffsll((long long)m) - 1;
                acc |= s_tile[buf][q][lane];   // banks (q+lane)&31: clean
                m &= m - 1ull;
            }
            rw |= acc;
        }
        __syncthreads();
    }
}

// ---------------------------------------------------------------------------
// K4: streaming mask of all outputs; NT hints on the 128 MB feature stream
// (ext_vector_type alias -- HIP_vector_type is not a legal NT-builtin operand).
// ---------------------------------------------------------------------------
__global__ __launch_bounds__(256) void mask_kernel(
    const float* __restrict__ centers,
    const float* __restrict__ features,
    const float* __restrict__ cls_preds,
    const float* __restrict__ keep,
    float* __restrict__ out_centers,
    float* __restrict__ out_feat,
    float* __restrict__ out_cls)
{
    const int idx = blockIdx.x * 256 + threadIdx.x;
    if (idx < FEAT4) {
        const int row = idx >> 8;                    // C/4 = 256 f4 per row
        const float m = keep[row];
        f4 v = __builtin_nontemporal_load(((const f4*)features) + idx);
        v.x *= m; v.y *= m; v.z *= m; v.w *= m;
        __builtin_nontemporal_store(v, ((f4*)out_feat) + idx);
    } else if (idx < FEAT4 + CEN4) {
        const int q = idx - FEAT4;
        float4 v = ((const float4*)centers)[q];
        const int e = q * 4;
        v.x *= keep[(e    ) / 3]; v.y *= keep[(e + 1) / 3];
        v.z *= keep[(e + 2) / 3]; v.w *= keep[(e + 3) / 3];
        ((float4*)out_centers)[q] = v;
    } else if (idx < FEAT4 + 2 * CEN4) {
        const int q = idx - FEAT4 - CEN4;
        float4 v = ((const float4*)cls_preds)[q];
        const int e = q * 4;
        v.x *= keep[(e    ) / 3]; v.y *= keep[(e + 1) / 3];
        v.z *= keep[(e + 2) / 3]; v.w *= keep[(e + 3) / 3];
        ((float4*)out_cls)[q] = v;
    }
}

extern "C" void kernel_launch(void* const* d_in, const int* in_sizes, int n_in,
                              void* d_out, int out_size, void* d_ws, size_t ws_size,
                              hipStream_t stream) {
    const float* centers      = (const float*)d_in[0];
    const float* features     = (const float*)d_in[1];
    const float* cls_preds    = (const float*)d_in[2];
    const float* class_radius = (const float*)d_in[3];

    float* out = (float*)d_out;
    float* out_centers = out;                                   // B*P*3
    float* out_feat    = out + (size_t)B * P * 3;               // B*P*C
    float* out_cls     = out_feat + (size_t)B * P * C;          // B*P*K
    float* out_keep    = out_cls + (size_t)B * P * 3;           // B*P

    // scratch inside out_feat (64 MB), fully rewritten by mask_kernel:
    //   matT  : 1,048,576 u32 (4 MB), layout matT[b][w][i]
    //   scent :    16,384 float4
    //   sidx  :    16,384 int
    u32*    matT  = (u32*)out_feat;
    float4* scent = (float4*)(out_feat + 1048576);
    int*    sidx  = (int*)(out_feat + 1048576 + 65536);

    hipLaunchKernelGGL(rank_kernel, dim3(B * 32), dim3(512), 0, stream,
                       centers, cls_preds, scent, sidx);
    hipLaunchKernelGGL(matrix_kernel, dim3(B * 32), dim3(512), 0, stream,
                       scent, class_radius, matT);
    hipLaunchKernelGGL(scan_kernel, dim3(B), dim3(576), 0, stream,
                       matT, sidx, out_keep);
    hipLaunchKernelGGL(mask_kernel, dim3((FEAT4 + 2 * CEN4 + 255) / 256), dim3(256),
                       0, stream,
                       centers, features, cls_preds, out_keep,
                       out_centers, out_feat, out_cls);
}

// Round 10
// 181.067 us; speedup vs baseline: 1.0897x; 1.0897x over previous
//
#include <hip/hip_runtime.h>

#define B 8
#define P 2048
#define C 1024
#define NCHUNK 32
#define FEAT4 (B*P*C/4)   // 4194304 float4s of features
#define CEN4  (B*P*3/4)   // 12288 float4s of centers (and of cls_preds)

typedef unsigned long long u64;
typedef unsigned int u32;

// ---------------------------------------------------------------------------
// K1: full-GPU rank sort (R7, unchanged). Keys unique => rank is a bijection.
// ---------------------------------------------------------------------------
__global__ __launch_bounds__(512) void rank_kernel(
    const float* __restrict__ centers,
    const float* __restrict__ cls_preds,
    float4* __restrict__ scent,
    int* __restrict__ sidx)
{
    __shared__ u64 s_keys[P];       // 16 KB
    __shared__ u32 s_cnt[64][9];    // padded reduce buffer
    const int b = blockIdx.x >> 5, gi = blockIdx.x & 31;
    const int tid = threadIdx.x, wv = tid >> 6, lane = tid & 63;
    const float* clsb = cls_preds + (size_t)b * P * 3;
    const float* cenb = centers + (size_t)b * P * 3;

    for (int e = tid; e < P; e += 512) {
        float s0 = clsb[e*3], s1 = clsb[e*3+1], s2 = clsb[e*3+2];
        float sc = s0; int lb = 0;
        if (s1 > sc) { sc = s1; lb = 1; }
        if (s2 > sc) { sc = s2; lb = 2; }
        u32 ub = __float_as_uint(sc);
        u32 ord = (ub & 0x80000000u) ? ~ub : (ub | 0x80000000u);
        s_keys[e] = ((u64)(~ord) << 32) | (u32)((e << 2) | lb);
    }
    __syncthreads();

    const u64 myk = s_keys[(gi << 6) + lane];
    u32 c = 0;
    const int sbase = wv << 8;
    #pragma unroll 8
    for (int u = 0; u < 256; ++u)            // wave-uniform -> broadcast, free
        c += (s_keys[sbase + u] < myk) ? 1u : 0u;
    s_cnt[lane][wv] = c;
    __syncthreads();

    if (wv == 0) {
        u32 rank = 0;
        #pragma unroll
        for (int s = 0; s < 8; ++s) rank += s_cnt[lane][s];
        u32 lo = (u32)myk;
        int orig = (int)(lo >> 2);
        float4 cc;
        cc.x = cenb[orig*3]; cc.y = cenb[orig*3+1]; cc.z = cenb[orig*3+2];
        cc.w = __int_as_float((int)(lo & 3));
        scent[(size_t)b * P + rank] = cc;
        sidx[(size_t)b * P + rank] = (int)lo;
    }
}

// ---------------------------------------------------------------------------
// K2: suppression rows, triangle-trimmed (scan only consumes matT[w][i] with
// w >= 2*(i/64); sub-diagonal words left as poison -- harmless, see K3 proof).
// ---------------------------------------------------------------------------
__global__ __launch_bounds__(512) void matrix_kernel(
    const float4* __restrict__ scent,
    const float* __restrict__ class_radius,
    u32* __restrict__ matT)
{
    __shared__ float4 s_cent[P];   // 32 KB
    const int b = blockIdx.x >> 5, gi = blockIdx.x & 31;
    const int tid = threadIdx.x, wv = tid >> 6, lane = tid & 63;

    const float4 cj = scent[(size_t)b * P + (gi << 6) + lane];  // coalesced
    const int labj = __float_as_int(cj.w);
    const float r = class_radius[labj];
    const float r2 = r * r;
    const int wmin = gi << 1;

    for (int i = tid; i < P; i += 512) s_cent[i] = scent[(size_t)b * P + i];
    __syncthreads();

    for (int w = wv; w < 64; w += 8) {
        if (w < wmin) continue;                       // dead sub-diagonal
        u32 acc = 0;
        #pragma unroll
        for (int u = 0; u < 32; ++u) {
            float4 ci = s_cent[(w << 5) + u];         // uniform -> broadcast
            float dx = cj.x - ci.x, dy = cj.y - ci.y, dz = cj.z - ci.z;
            bool sup = (__float_as_int(ci.w) == labj)
                       && (dx*dx + dy*dy + dz*dz < r2);
            acc |= ((u32)sup) << u;
        }
        matT[((size_t)b * 64 + w) * P + (gi << 6) + lane] = acc;  // coalesced
    }
}

// ---------------------------------------------------------------------------
// K3: greedy resolution, one block (9 waves) per scene, one barrier/chunk,
// PREFETCH DEPTH 3 (quad-buffered tiles): loads for chunk g+3 issue at chunk
// g, giving ~3 chunk-periods to land -> the L2/HBM round-trip (the R9
// bottleneck: 3400 cyc/chunk measured vs ~500 of work) is fully overlapped.
// Full 64-word tile loads (R7's known-good issue order). Garbage-word proof:
// tile of chunk c has valid words w >= 2c (matrix trim). Update at chunk c
// ORs all words into s_removed; garbage lands only in s_removed[w], w < 2c,
// and chunk w/2 < c was already resolved -- those words are never read again.
// ---------------------------------------------------------------------------
__global__ __launch_bounds__(576) void scan_kernel(
    const u32* __restrict__ matT,
    const int* __restrict__ sidx,
    float* __restrict__ out_keep)
{
    __shared__ u32 s_tile[4][64][65];   // [buf][q][w]; 66.5 KB, 4-deep
    __shared__ u32 s_removed[64];
    __shared__ int s_sidx[P];
    const int b = blockIdx.x;
    const int tid = threadIdx.x, wv = tid >> 6, lane = tid & 63;
    const u32* mb = matT + (size_t)b * 64 * P;

    for (int i = tid; i < P; i += 576) s_sidx[i] = sidx[(size_t)b * P + i];
    if (tid < 64) s_removed[tid] = 0;
    if (wv >= 1) {                       // stage chunks 0..2 into bufs 0..2
        #pragma unroll
        for (int c = 0; c < 3; ++c) {
            #pragma unroll
            for (int rr = 0; rr < 8; ++rr) {
                int w = ((wv - 1) << 3) + rr;
                s_tile[c][lane][w] = mb[(size_t)w * P + (c << 6) + lane];
            }
        }
    }
    __syncthreads();

    for (int g = 0; g < NCHUNK; ++g) {
        const int buf = g & 3;
        if (wv >= 1 && g + 3 < NCHUNK) { // prefetch chunk g+3, 3 periods ahead
            const int nb = (g + 3) << 6;
            #pragma unroll
            for (int rr = 0; rr < 8; ++rr) {
                int w = ((wv - 1) << 3) + rr;
                s_tile[(g + 3) & 3][lane][w] = mb[(size_t)w * P + nb + lane];
            }
        }
        if (wv == 0) {
            const int base = g << 6;
            u64 row = (u64)s_tile[buf][lane][2*g]
                    | ((u64)s_tile[buf][lane][2*g + 1] << 32);
            u64 rem = (u64)s_removed[2*g] | ((u64)s_removed[2*g + 1] << 32);
            u64 alive = ~rem;
            const u64 below = (1ull << lane) - 1ull;
            u64 keepm = 0;
            while (alive) {              // peeling: rounds = chain depth
                bool ok = ((alive >> lane) & 1ull) && ((row & alive & below) == 0ull);
                u64 newk = __ballot(ok);
                keepm |= newk;
                bool dead = (row & newk) != 0ull;
                u64 deadm = __ballot(dead);
                alive &= ~(newk | deadm);
            }
            int orig = s_sidx[base + lane] >> 2;
            out_keep[(size_t)b * P + orig] = ((keepm >> lane) & 1ull) ? 1.0f : 0.0f;
            // incremental removed update: lane == word index
            u32 acc = 0;
            u64 m = keepm;
            while (m) {
                int q = (int)__ffsll((long long)m) - 1;
                acc |= s_tile[buf][q][lane];   // banks (q+lane)&31: clean
                m &= m - 1ull;
            }
            s_removed[lane] |= acc;
        }
        __syncthreads();
    }
}

// ---------------------------------------------------------------------------
// K4: streaming mask of all outputs (plain float4 -- R7 known-good form).
// ---------------------------------------------------------------------------
__global__ __launch_bounds__(256) void mask_kernel(
    const float* __restrict__ centers,
    const float* __restrict__ features,
    const float* __restrict__ cls_preds,
    const float* __restrict__ keep,
    float* __restrict__ out_centers,
    float* __restrict__ out_feat,
    float* __restrict__ out_cls)
{
    const int idx = blockIdx.x * 256 + threadIdx.x;
    if (idx < FEAT4) {
        const int row = idx >> 8;                    // C/4 = 256 f4 per row
        const float m = keep[row];
        float4 v = ((const float4*)features)[idx];
        v.x *= m; v.y *= m; v.z *= m; v.w *= m;
        ((float4*)out_feat)[idx] = v;
    } else if (idx < FEAT4 + CEN4) {
        const int q = idx - FEAT4;
        float4 v = ((const float4*)centers)[q];
        const int e = q * 4;
        v.x *= keep[(e    ) / 3]; v.y *= keep[(e + 1) / 3];
        v.z *= keep[(e + 2) / 3]; v.w *= keep[(e + 3) / 3];
        ((float4*)out_centers)[q] = v;
    } else if (idx < FEAT4 + 2 * CEN4) {
        const int q = idx - FEAT4 - CEN4;
        float4 v = ((const float4*)cls_preds)[q];
        const int e = q * 4;
        v.x *= keep[(e    ) / 3]; v.y *= keep[(e + 1) / 3];
        v.z *= keep[(e + 2) / 3]; v.w *= keep[(e + 3) / 3];
        ((float4*)out_cls)[q] = v;
    }
}

extern "C" void kernel_launch(void* const* d_in, const int* in_sizes, int n_in,
                              void* d_out, int out_size, void* d_ws, size_t ws_size,
                              hipStream_t stream) {
    const float* centers      = (const float*)d_in[0];
    const float* features     = (const float*)d_in[1];
    const float* cls_preds    = (const float*)d_in[2];
    const float* class_radius = (const float*)d_in[3];

    float* out = (float*)d_out;
    float* out_centers = out;                                   // B*P*3
    float* out_feat    = out + (size_t)B * P * 3;               // B*P*C
    float* out_cls     = out_feat + (size_t)B * P * C;          // B*P*K
    float* out_keep    = out_cls + (size_t)B * P * 3;           // B*P

    // scratch inside out_feat (64 MB), fully rewritten by mask_kernel:
    //   matT  : 1,048,576 u32 (4 MB), layout matT[b][w][i]
    //   scent :    16,384 float4
    //   sidx  :    16,384 int
    u32*    matT  = (u32*)out_feat;
    float4* scent = (float4*)(out_feat + 1048576);
    int*    sidx  = (int*)(out_feat + 1048576 + 65536);

    hipLaunchKernelGGL(rank_kernel, dim3(B * 32), dim3(512), 0, stream,
                       centers, cls_preds, scent, sidx);
    hipLaunchKernelGGL(matrix_kernel, dim3(B * 32), dim3(512), 0, stream,
                       scent, class_radius, matT);
    hipLaunchKernelGGL(scan_kernel, dim3(B), dim3(576), 0, stream,
                       matT, sidx, out_keep);
    hipLaunchKernelGGL(mask_kernel, dim3((FEAT4 + 2 * CEN4 + 255) / 256), dim3(256),
                       0, stream,
                       centers, features, cls_preds, out_keep,
                       out_centers, out_feat, out_cls);
}

// Round 11
// 173.049 us; speedup vs baseline: 1.1401x; 1.0463x over previous
//
#include <hip/hip_runtime.h>

#define B 8
#define P 2048
#define C 1024
#define NCHUNK 32
#define FEAT4 (B*P*C/4)   // 4194304 float4s of features
#define CEN4  (B*P*3/4)   // 12288 float4s of centers (and of cls_preds)

typedef unsigned long long u64;
typedef unsigned int u32;

// ---------------------------------------------------------------------------
// K1: full-GPU rank sort (R7, unchanged). Keys unique => rank is a bijection.
// ---------------------------------------------------------------------------
__global__ __launch_bounds__(512) void rank_kernel(
    const float* __restrict__ centers,
    const float* __restrict__ cls_preds,
    float4* __restrict__ scent,
    int* __restrict__ sidx)
{
    __shared__ u64 s_keys[P];       // 16 KB
    __shared__ u32 s_cnt[64][9];    // padded reduce buffer
    const int b = blockIdx.x >> 5, gi = blockIdx.x & 31;
    const int tid = threadIdx.x, wv = tid >> 6, lane = tid & 63;
    const float* clsb = cls_preds + (size_t)b * P * 3;
    const float* cenb = centers + (size_t)b * P * 3;

    for (int e = tid; e < P; e += 512) {
        float s0 = clsb[e*3], s1 = clsb[e*3+1], s2 = clsb[e*3+2];
        float sc = s0; int lb = 0;
        if (s1 > sc) { sc = s1; lb = 1; }
        if (s2 > sc) { sc = s2; lb = 2; }
        u32 ub = __float_as_uint(sc);
        u32 ord = (ub & 0x80000000u) ? ~ub : (ub | 0x80000000u);
        s_keys[e] = ((u64)(~ord) << 32) | (u32)((e << 2) | lb);
    }
    __syncthreads();

    const u64 myk = s_keys[(gi << 6) + lane];
    u32 c = 0;
    const int sbase = wv << 8;
    #pragma unroll 8
    for (int u = 0; u < 256; ++u)            // wave-uniform -> broadcast, free
        c += (s_keys[sbase + u] < myk) ? 1u : 0u;
    s_cnt[lane][wv] = c;
    __syncthreads();

    if (wv == 0) {
        u32 rank = 0;
        #pragma unroll
        for (int s = 0; s < 8; ++s) rank += s_cnt[lane][s];
        u32 lo = (u32)myk;
        int orig = (int)(lo >> 2);
        float4 cc;
        cc.x = cenb[orig*3]; cc.y = cenb[orig*3+1]; cc.z = cenb[orig*3+2];
        cc.w = __int_as_float((int)(lo & 3));
        scent[(size_t)b * P + rank] = cc;
        sidx[(size_t)b * P + rank] = (int)lo;
    }
}

// ---------------------------------------------------------------------------
// K2: suppression rows, triangle-trimmed (scan only consumes matT[w][i] with
// w >= 2*(i/64); sub-diagonal words left as poison -- harmless, see K3 proof).
// ---------------------------------------------------------------------------
__global__ __launch_bounds__(512) void matrix_kernel(
    const float4* __restrict__ scent,
    const float* __restrict__ class_radius,
    u32* __restrict__ matT)
{
    __shared__ float4 s_cent[P];   // 32 KB
    const int b = blockIdx.x >> 5, gi = blockIdx.x & 31;
    const int tid = threadIdx.x, wv = tid >> 6, lane = tid & 63;

    const float4 cj = scent[(size_t)b * P + (gi << 6) + lane];  // coalesced
    const int labj = __float_as_int(cj.w);
    const float r = class_radius[labj];
    const float r2 = r * r;
    const int wmin = gi << 1;

    for (int i = tid; i < P; i += 512) s_cent[i] = scent[(size_t)b * P + i];
    __syncthreads();

    for (int w = wv; w < 64; w += 8) {
        if (w < wmin) continue;                       // dead sub-diagonal
        u32 acc = 0;
        #pragma unroll
        for (int u = 0; u < 32; ++u) {
            float4 ci = s_cent[(w << 5) + u];         // uniform -> broadcast
            float dx = cj.x - ci.x, dy = cj.y - ci.y, dz = cj.z - ci.z;
            bool sup = (__float_as_int(ci.w) == labj)
                       && (dx*dx + dy*dy + dz*dz < r2);
            acc |= ((u32)sup) << u;
        }
        matT[((size_t)b * 64 + w) * P + (gi << 6) + lane] = acc;  // coalesced
    }
}

// ---------------------------------------------------------------------------
// K3: greedy resolution -- REGISTER-RESIDENT tiles, barrier-transparent
// prefetch. R10's LDS-staged prefetch was defeated by the compiler's
// mandatory `s_waitcnt vmcnt(0)` before s_barrier (ds_write of load data must
// drain). Register loads carry no such obligation: they stay in flight
// across barriers and are waited on only at USE, 3 chunks after issue.
//   waves 1..8: wave w lane l holds words w'=l of rows q in [8(w-1),8w)
//               (2 x uint4 per slot, 4 slots, depth-3 prefetch).
//   wave 0:     2 resolve words/chunk in registers (same depth).
//   loop: [issue g+3 prefetch] [wave0: peel-resolve -> s_keepm[g]]
//         [barrier] [waves 1-8: 8 predicated ORs + LDS atomicOr into
//         s_removed] [barrier].  No global stores in the loop (keep scatter
//         moved to a cooperative tail) -> barriers fence only LDS.
// g-loop fully unrolled so slot indices are compile-time (no scratch).
// Garbage-word proof: word l of a chunk-c row is valid iff l >= 2c; garbage
// ORs land only in s_removed[l], l < 2c, which was last read at chunk
// l/2 < c -- strictly before the write. Reads only ever see valid words.
// ---------------------------------------------------------------------------
__global__ __launch_bounds__(576) void scan_kernel(
    const u32* __restrict__ matT,
    const int* __restrict__ sidx,
    float* __restrict__ out_keep)
{
    __shared__ int s_sidx[P];
    __shared__ u32 s_removed[64];
    __shared__ u64 s_keepm[NCHUNK];
    const int b = blockIdx.x;
    const int tid = threadIdx.x, wv = tid >> 6, lane = tid & 63;
    const u32* mb = matT + (size_t)b * 64 * P;

    for (int i = tid; i < P; i += 576) s_sidx[i] = sidx[(size_t)b * P + i];
    if (tid < 64) s_removed[tid] = 0;

    uint4 Va[4], Vb[4];                  // waves 1..8: tile slots (regs)
    u32 Ra[4], Rb[4];                    // wave 0: resolve-row slots (regs)
    const int qb = (wv - 1) << 3;        // wave's q-base (valid for wv>=1)

    #pragma unroll
    for (int c = 0; c < 3; ++c) {        // preload chunks 0..2
        if (wv >= 1) {
            const u32* p = mb + (size_t)lane * P + (c << 6) + qb;
            Va[c] = *(const uint4*)p;
            Vb[c] = *(const uint4*)(p + 4);
        } else {
            Ra[c] = mb[(size_t)(2*c    ) * P + (c << 6) + lane];
            Rb[c] = mb[(size_t)(2*c + 1) * P + (c << 6) + lane];
        }
    }
    __syncthreads();

    #pragma unroll                        // FULL unroll: slot = g&3 constant
    for (int g = 0; g < NCHUNK; ++g) {
        const int slot = g & 3;
        if (g + 3 < NCHUNK) {             // issue prefetch for chunk g+3
            const int c = g + 3, ns = c & 3;
            if (wv >= 1) {
                const u32* p = mb + (size_t)lane * P + (c << 6) + qb;
                Va[ns] = *(const uint4*)p;
                Vb[ns] = *(const uint4*)(p + 4);
            } else {
                Ra[ns] = mb[(size_t)(2*c    ) * P + (c << 6) + lane];
                Rb[ns] = mb[(size_t)(2*c + 1) * P + (c << 6) + lane];
            }
        }
        if (wv == 0) {
            u64 row = (u64)Ra[slot] | ((u64)Rb[slot] << 32);
            u64 rem = (u64)s_removed[2*g] | ((u64)s_removed[2*g + 1] << 32);
            u64 alive = ~rem;
            const u64 below = (1ull << lane) - 1ull;
            u64 keepm = 0;
            while (alive) {               // peeling: rounds = chain depth
                bool ok = ((alive >> lane) & 1ull) && ((row & alive & below) == 0ull);
                u64 newk = __ballot(ok);
                keepm |= newk;
                bool dead = (row & newk) != 0ull;
                u64 deadm = __ballot(dead);
                alive &= ~(newk | deadm);
            }
            if (lane == 0) s_keepm[g] = keepm;
        }
        __syncthreads();                  // fences LDS only: no vmcnt drain
        if (wv >= 1) {                    // distributed removed-update
            const u32 kb = (u32)(s_keepm[g] >> qb) & 0xffu;
            u32 acc = 0;
            if (kb & 0x01u) acc |= Va[slot].x;
            if (kb & 0x02u) acc |= Va[slot].y;
            if (kb & 0x04u) acc |= Va[slot].z;
            if (kb & 0x08u) acc |= Va[slot].w;
            if (kb & 0x10u) acc |= Vb[slot].x;
            if (kb & 0x20u) acc |= Vb[slot].y;
            if (kb & 0x40u) acc |= Vb[slot].z;
            if (kb & 0x80u) acc |= Vb[slot].w;
            if (acc) atomicOr(&s_removed[lane], acc);
        }
        __syncthreads();
    }

    // tail: one cooperative keep-scatter (the loop's only global side effect)
    for (int pos = tid; pos < P; pos += 576) {
        u64 km = s_keepm[pos >> 6];
        int orig = s_sidx[pos] >> 2;
        out_keep[(size_t)b * P + orig] = ((km >> (pos & 63)) & 1ull) ? 1.0f : 0.0f;
    }
}

// ---------------------------------------------------------------------------
// K4: streaming mask of all outputs (plain float4 -- known-good form).
// ---------------------------------------------------------------------------
__global__ __launch_bounds__(256) void mask_kernel(
    const float* __restrict__ centers,
    const float* __restrict__ features,
    const float* __restrict__ cls_preds,
    const float* __restrict__ keep,
    float* __restrict__ out_centers,
    float* __restrict__ out_feat,
    float* __restrict__ out_cls)
{
    const int idx = blockIdx.x * 256 + threadIdx.x;
    if (idx < FEAT4) {
        const int row = idx >> 8;                    // C/4 = 256 f4 per row
        const float m = keep[row];
        float4 v = ((const float4*)features)[idx];
        v.x *= m; v.y *= m; v.z *= m; v.w *= m;
        ((float4*)out_feat)[idx] = v;
    } else if (idx < FEAT4 + CEN4) {
        const int q = idx - FEAT4;
        float4 v = ((const float4*)centers)[q];
        const int e = q * 4;
        v.x *= keep[(e    ) / 3]; v.y *= keep[(e + 1) / 3];
        v.z *= keep[(e + 2) / 3]; v.w *= keep[(e + 3) / 3];
        ((float4*)out_centers)[q] = v;
    } else if (idx < FEAT4 + 2 * CEN4) {
        const int q = idx - FEAT4 - CEN4;
        float4 v = ((const float4*)cls_preds)[q];
        const int e = q * 4;
        v.x *= keep[(e    ) / 3]; v.y *= keep[(e + 1) / 3];
        v.z *= keep[(e + 2) / 3]; v.w *= keep[(e + 3) / 3];
        ((float4*)out_cls)[q] = v;
    }
}

extern "C" void kernel_launch(void* const* d_in, const int* in_sizes, int n_in,
                              void* d_out, int out_size, void* d_ws, size_t ws_size,
                              hipStream_t stream) {
    const float* centers      = (const float*)d_in[0];
    const float* features     = (const float*)d_in[1];
    const float* cls_preds    = (const float*)d_in[2];
    const float* class_radius = (const float*)d_in[3];

    float* out = (float*)d_out;
    float* out_centers = out;                                   // B*P*3
    float* out_feat    = out + (size_t)B * P * 3;               // B*P*C
    float* out_cls     = out_feat + (size_t)B * P * C;          // B*P*K
    float* out_keep    = out_cls + (size_t)B * P * 3;           // B*P

    // scratch inside out_feat (64 MB), fully rewritten by mask_kernel:
    //   matT  : 1,048,576 u32 (4 MB), layout matT[b][w][i]
    //   scent :    16,384 float4
    //   sidx  :    16,384 int
    u32*    matT  = (u32*)out_feat;
    float4* scent = (float4*)(out_feat + 1048576);
    int*    sidx  = (int*)(out_feat + 1048576 + 65536);

    hipLaunchKernelGGL(rank_kernel, dim3(B * 32), dim3(512), 0, stream,
                       centers, cls_preds, scent, sidx);
    hipLaunchKernelGGL(matrix_kernel, dim3(B * 32), dim3(512), 0, stream,
                       scent, class_radius, matT);
    hipLaunchKernelGGL(scan_kernel, dim3(B), dim3(576), 0, stream,
                       matT, sidx, out_keep);
    hipLaunchKernelGGL(mask_kernel, dim3((FEAT4 + 2 * CEN4 + 255) / 256), dim3(256),
                       0, stream,
                       centers, features, cls_preds, out_keep,
                       out_centers, out_feat, out_cls);
}

// Round 12
// 171.495 us; speedup vs baseline: 1.1505x; 1.0091x over previous
//
#include <hip/hip_runtime.h>

#define B 8
#define P 2048
#define C 1024
#define NCHUNK 32
#define FEAT4 (B*P*C/4)   // 4194304 float4s of features
#define CEN4  (B*P*3/4)   // 12288 float4s of centers (and of cls_preds)

typedef unsigned long long u64;
typedef unsigned int u32;

// ---------------------------------------------------------------------------
// K1: full-GPU rank sort (R7, unchanged). Keys unique => rank is a bijection.
// ---------------------------------------------------------------------------
__global__ __launch_bounds__(512) void rank_kernel(
    const float* __restrict__ centers,
    const float* __restrict__ cls_preds,
    float4* __restrict__ scent,
    int* __restrict__ sidx)
{
    __shared__ u64 s_keys[P];       // 16 KB
    __shared__ u32 s_cnt[64][9];    // padded reduce buffer
    const int b = blockIdx.x >> 5, gi = blockIdx.x & 31;
    const int tid = threadIdx.x, wv = tid >> 6, lane = tid & 63;
    const float* clsb = cls_preds + (size_t)b * P * 3;
    const float* cenb = centers + (size_t)b * P * 3;

    for (int e = tid; e < P; e += 512) {
        float s0 = clsb[e*3], s1 = clsb[e*3+1], s2 = clsb[e*3+2];
        float sc = s0; int lb = 0;
        if (s1 > sc) { sc = s1; lb = 1; }
        if (s2 > sc) { sc = s2; lb = 2; }
        u32 ub = __float_as_uint(sc);
        u32 ord = (ub & 0x80000000u) ? ~ub : (ub | 0x80000000u);
        s_keys[e] = ((u64)(~ord) << 32) | (u32)((e << 2) | lb);
    }
    __syncthreads();

    const u64 myk = s_keys[(gi << 6) + lane];
    u32 c = 0;
    const int sbase = wv << 8;
    #pragma unroll 8
    for (int u = 0; u < 256; ++u)            // wave-uniform -> broadcast, free
        c += (s_keys[sbase + u] < myk) ? 1u : 0u;
    s_cnt[lane][wv] = c;
    __syncthreads();

    if (wv == 0) {
        u32 rank = 0;
        #pragma unroll
        for (int s = 0; s < 8; ++s) rank += s_cnt[lane][s];
        u32 lo = (u32)myk;
        int orig = (int)(lo >> 2);
        float4 cc;
        cc.x = cenb[orig*3]; cc.y = cenb[orig*3+1]; cc.z = cenb[orig*3+2];
        cc.w = __int_as_float((int)(lo & 3));
        scent[(size_t)b * P + rank] = cc;
        sidx[(size_t)b * P + rank] = (int)lo;
    }
}

// ---------------------------------------------------------------------------
// K2: suppression rows, triangle-trimmed (scan only consumes matT[w][i] with
// w >= 2*(i/64); sub-diagonal words left as poison -- harmless, see K3 proof).
// ---------------------------------------------------------------------------
__global__ __launch_bounds__(512) void matrix_kernel(
    const float4* __restrict__ scent,
    const float* __restrict__ class_radius,
    u32* __restrict__ matT)
{
    __shared__ float4 s_cent[P];   // 32 KB
    const int b = blockIdx.x >> 5, gi = blockIdx.x & 31;
    const int tid = threadIdx.x, wv = tid >> 6, lane = tid & 63;

    const float4 cj = scent[(size_t)b * P + (gi << 6) + lane];  // coalesced
    const int labj = __float_as_int(cj.w);
    const float r = class_radius[labj];
    const float r2 = r * r;
    const int wmin = gi << 1;

    for (int i = tid; i < P; i += 512) s_cent[i] = scent[(size_t)b * P + i];
    __syncthreads();

    for (int w = wv; w < 64; w += 8) {
        if (w < wmin) continue;                       // dead sub-diagonal
        u32 acc = 0;
        #pragma unroll
        for (int u = 0; u < 32; ++u) {
            float4 ci = s_cent[(w << 5) + u];         // uniform -> broadcast
            float dx = cj.x - ci.x, dy = cj.y - ci.y, dz = cj.z - ci.z;
            bool sup = (__float_as_int(ci.w) == labj)
                       && (dx*dx + dy*dy + dz*dz < r2);
            acc |= ((u32)sup) << u;
        }
        matT[((size_t)b * 64 + w) * P + (gi << 6) + lane] = acc;  // coalesced
    }
}

// ---------------------------------------------------------------------------
// K3: greedy resolution -- register-resident tiles, barrier-transparent
// depth-3 prefetch (R11, unchanged -- verified fastest). Register loads
// carry no vmcnt obligation at s_barrier; waited on only at use, 3 chunks
// after issue. Keep scatter moved to a cooperative tail so loop barriers
// fence LDS only.
// ---------------------------------------------------------------------------
__global__ __launch_bounds__(576) void scan_kernel(
    const u32* __restrict__ matT,
    const int* __restrict__ sidx,
    float* __restrict__ out_keep)
{
    __shared__ int s_sidx[P];
    __shared__ u32 s_removed[64];
    __shared__ u64 s_keepm[NCHUNK];
    const int b = blockIdx.x;
    const int tid = threadIdx.x, wv = tid >> 6, lane = tid & 63;
    const u32* mb = matT + (size_t)b * 64 * P;

    for (int i = tid; i < P; i += 576) s_sidx[i] = sidx[(size_t)b * P + i];
    if (tid < 64) s_removed[tid] = 0;

    uint4 Va[4], Vb[4];                  // waves 1..8: tile slots (regs)
    u32 Ra[4], Rb[4];                    // wave 0: resolve-row slots (regs)
    const int qb = (wv - 1) << 3;        // wave's q-base (valid for wv>=1)

    #pragma unroll
    for (int c = 0; c < 3; ++c) {        // preload chunks 0..2
        if (wv >= 1) {
            const u32* p = mb + (size_t)lane * P + (c << 6) + qb;
            Va[c] = *(const uint4*)p;
            Vb[c] = *(const uint4*)(p + 4);
        } else {
            Ra[c] = mb[(size_t)(2*c    ) * P + (c << 6) + lane];
            Rb[c] = mb[(size_t)(2*c + 1) * P + (c << 6) + lane];
        }
    }
    __syncthreads();

    #pragma unroll                        // FULL unroll: slot = g&3 constant
    for (int g = 0; g < NCHUNK; ++g) {
        const int slot = g & 3;
        if (g + 3 < NCHUNK) {             // issue prefetch for chunk g+3
            const int c = g + 3, ns = c & 3;
            if (wv >= 1) {
                const u32* p = mb + (size_t)lane * P + (c << 6) + qb;
                Va[ns] = *(const uint4*)p;
                Vb[ns] = *(const uint4*)(p + 4);
            } else {
                Ra[ns] = mb[(size_t)(2*c    ) * P + (c << 6) + lane];
                Rb[ns] = mb[(size_t)(2*c + 1) * P + (c << 6) + lane];
            }
        }
        if (wv == 0) {
            u64 row = (u64)Ra[slot] | ((u64)Rb[slot] << 32);
            u64 rem = (u64)s_removed[2*g] | ((u64)s_removed[2*g + 1] << 32);
            u64 alive = ~rem;
            const u64 below = (1ull << lane) - 1ull;
            u64 keepm = 0;
            while (alive) {               // peeling: rounds = chain depth
                bool ok = ((alive >> lane) & 1ull) && ((row & alive & below) == 0ull);
                u64 newk = __ballot(ok);
                keepm |= newk;
                bool dead = (row & newk) != 0ull;
                u64 deadm = __ballot(dead);
                alive &= ~(newk | deadm);
            }
            if (lane == 0) s_keepm[g] = keepm;
        }
        __syncthreads();                  // fences LDS only: no vmcnt drain
        if (wv >= 1) {                    // distributed removed-update
            const u32 kb = (u32)(s_keepm[g] >> qb) & 0xffu;
            u32 acc = 0;
            if (kb & 0x01u) acc |= Va[slot].x;
            if (kb & 0x02u) acc |= Va[slot].y;
            if (kb & 0x04u) acc |= Va[slot].z;
            if (kb & 0x08u) acc |= Va[slot].w;
            if (kb & 0x10u) acc |= Vb[slot].x;
            if (kb & 0x20u) acc |= Vb[slot].y;
            if (kb & 0x40u) acc |= Vb[slot].z;
            if (kb & 0x80u) acc |= Vb[slot].w;
            if (acc) atomicOr(&s_removed[lane], acc);
        }
        __syncthreads();
    }

    // tail: one cooperative keep-scatter (the loop's only global side effect)
    for (int pos = tid; pos < P; pos += 576) {
        u64 km = s_keepm[pos >> 6];
        int orig = s_sidx[pos] >> 2;
        out_keep[(size_t)b * P + orig] = ((km >> (pos & 63)) & 1ull) ? 1.0f : 0.0f;
    }
}

// ---------------------------------------------------------------------------
// K4: streaming mask. NEW: suppressed feature rows (keep==0, the ~90-98%
// majority under radius-NMS) are written as zeros WITHOUT loading the source
// row -- keep[row] is block-uniform (one 256-thread block == one C-row), so
// the skip branch has zero divergence and FETCH collapses to ~keep_frac*64MB.
// (f * 0.0f == -0.0f for negative f; |0 - (-0)| = 0 under absmax -- safe.)
// ---------------------------------------------------------------------------
__global__ __launch_bounds__(256) void mask_kernel(
    const float* __restrict__ centers,
    const float* __restrict__ features,
    const float* __restrict__ cls_preds,
    const float* __restrict__ keep,
    float* __restrict__ out_centers,
    float* __restrict__ out_feat,
    float* __restrict__ out_cls)
{
    const int idx = blockIdx.x * 256 + threadIdx.x;
    if (idx < FEAT4) {
        const int row = idx >> 8;                    // C/4 = 256 f4 per row
        const float m = keep[row];                   // block-uniform
        if (m != 0.0f) {
            float4 v = ((const float4*)features)[idx];
            v.x *= m; v.y *= m; v.z *= m; v.w *= m;
            ((float4*)out_feat)[idx] = v;
        } else {
            float4 z; z.x = 0.f; z.y = 0.f; z.z = 0.f; z.w = 0.f;
            ((float4*)out_feat)[idx] = z;            // store-only: no fetch
        }
    } else if (idx < FEAT4 + CEN4) {
        const int q = idx - FEAT4;
        float4 v = ((const float4*)centers)[q];
        const int e = q * 4;
        v.x *= keep[(e    ) / 3]; v.y *= keep[(e + 1) / 3];
        v.z *= keep[(e + 2) / 3]; v.w *= keep[(e + 3) / 3];
        ((float4*)out_centers)[q] = v;
    } else if (idx < FEAT4 + 2 * CEN4) {
        const int q = idx - FEAT4 - CEN4;
        float4 v = ((const float4*)cls_preds)[q];
        const int e = q * 4;
        v.x *= keep[(e    ) / 3]; v.y *= keep[(e + 1) / 3];
        v.z *= keep[(e + 2) / 3]; v.w *= keep[(e + 3) / 3];
        ((float4*)out_cls)[q] = v;
    }
}

extern "C" void kernel_launch(void* const* d_in, const int* in_sizes, int n_in,
                              void* d_out, int out_size, void* d_ws, size_t ws_size,
                              hipStream_t stream) {
    const float* centers      = (const float*)d_in[0];
    const float* features     = (const float*)d_in[1];
    const float* cls_preds    = (const float*)d_in[2];
    const float* class_radius = (const float*)d_in[3];

    float* out = (float*)d_out;
    float* out_centers = out;                                   // B*P*3
    float* out_feat    = out + (size_t)B * P * 3;               // B*P*C
    float* out_cls     = out_feat + (size_t)B * P * C;          // B*P*K
    float* out_keep    = out_cls + (size_t)B * P * 3;           // B*P

    // scratch inside out_feat (64 MB), fully rewritten by mask_kernel:
    //   matT  : 1,048,576 u32 (4 MB), layout matT[b][w][i]
    //   scent :    16,384 float4
    //   sidx  :    16,384 int
    u32*    matT  = (u32*)out_feat;
    float4* scent = (float4*)(out_feat + 1048576);
    int*    sidx  = (int*)(out_feat + 1048576 + 65536);

    hipLaunchKernelGGL(rank_kernel, dim3(B * 32), dim3(512), 0, stream,
                       centers, cls_preds, scent, sidx);
    hipLaunchKernelGGL(matrix_kernel, dim3(B * 32), dim3(512), 0, stream,
                       scent, class_radius, matT);
    hipLaunchKernelGGL(scan_kernel, dim3(B), dim3(576), 0, stream,
                       matT, sidx, out_keep);
    hipLaunchKernelGGL(mask_kernel, dim3((FEAT4 + 2 * CEN4 + 255) / 256), dim3(256),
                       0, stream,
                       centers, features, cls_preds, out_keep,
                       out_centers, out_feat, out_cls);
}